// Round 1
// baseline (1703.270 us; speedup 1.0000x reference)
//
#include <hip/hip_runtime.h>
#include <math.h>

#define N_Q 16384
#define N_M 16384
#define DIM 128
#define KNN 5
#define SPLITS 2
#define BN 64
#define BM 64
#define NTHREADS 256
#define COLS_PER_SPLIT (N_M / SPLITS)
#define TILES_PER_SPLIT (COLS_PER_SPLIT / BM)
#define BIGF 3.0e38f

// ---------------------------------------------------------------------------
// Kernel 1: per-row sum of squares for query (q2[N]) and memory bank (m2[M]).
// One wave (64 lanes) per row; lane reads float2, shuffle-reduce.
// ---------------------------------------------------------------------------
__global__ void row_sumsq_kernel(const float* __restrict__ q,
                                 const float* __restrict__ mem,
                                 float* __restrict__ q2,
                                 float* __restrict__ m2) {
    int gtid = blockIdx.x * blockDim.x + threadIdx.x;
    int wid  = gtid >> 6;
    int lane = gtid & 63;
    const float* src;
    float* dst;
    if (wid < N_Q) {
        src = q + (size_t)wid * DIM;
        dst = q2 + wid;
    } else {
        src = mem + (size_t)(wid - N_Q) * DIM;
        dst = m2 + (wid - N_Q);
    }
    float2 v = reinterpret_cast<const float2*>(src)[lane];
    float s = fmaf(v.x, v.x, v.y * v.y);
#pragma unroll
    for (int off = 32; off > 0; off >>= 1) s += __shfl_down(s, off, 64);
    if (lane == 0) *dst = s;
}

// ---------------------------------------------------------------------------
// Kernel 2: fused distance-GEMM + per-row top-5-smallest of s = m2 - 2*q.m
// Block: 256 threads, tile BN=64 queries x BM=64 memory cols, full D=128 in
// LDS. grid = (N/BN row-blocks, SPLITS column splits).
// LDS layout for tiles: element (k, c) at k*64 + 4*((c>>2) ^ (k&15)) + (c&3)
//   -> ds_read_b128 fragment reads are conflict-free, staging writes ~4-way.
// Each thread keeps running top-5 (val,idx) for its 4 rows over its 4-col
// stripe; end-of-kernel 16-way merge per row through (reused) LDS.
// ---------------------------------------------------------------------------
__global__ __launch_bounds__(NTHREADS) void knn_main_kernel(
    const float* __restrict__ query, const float* __restrict__ mem,
    const float* __restrict__ m2, float* __restrict__ candV,
    int* __restrict__ candI) {
    __shared__ __align__(16) float lds[16384];  // 64 KB: Qs [0,8192), Ms [8192,16384)
    __shared__ float m2s[BM];

    const int tid = threadIdx.x;
    const int tx = tid & 15;   // col group (4 cols)
    const int ty = tid >> 4;   // row group (4 rows)
    const int row0 = blockIdx.x * BN;
    const int colbase0 = blockIdx.y * COLS_PER_SPLIT;

    float* Qs = lds;
    float* Ms = lds + 8192;

    // ---- stage Q tile (once): global [r][d] -> LDS swizzled [d][r] ----
    {
        const float* gq = query + (size_t)row0 * DIM;
#pragma unroll
        for (int it = 0; it < 8; ++it) {
            int flat = tid + NTHREADS * it;  // 0..2047
            int r = flat >> 5;               // 0..63
            int c4 = flat & 31;              // float4 index along D
            float4 v = reinterpret_cast<const float4*>(gq + (size_t)r * DIM)[c4];
            int g = r >> 2, rl = r & 3;
            int d0 = c4 << 2;
            Qs[(d0 + 0) * 64 + ((g ^ ((d0 + 0) & 15)) << 2) + rl] = v.x;
            Qs[(d0 + 1) * 64 + ((g ^ ((d0 + 1) & 15)) << 2) + rl] = v.y;
            Qs[(d0 + 2) * 64 + ((g ^ ((d0 + 2) & 15)) << 2) + rl] = v.z;
            Qs[(d0 + 3) * 64 + ((g ^ ((d0 + 3) & 15)) << 2) + rl] = v.w;
        }
    }

    // ---- running top-5 state: 4 rows x 5 (val,idx), max-replace scheme ----
    float tv[4][KNN];
    int   tix[4][KNN];
    float mx[4];
    int   ms[4];
#pragma unroll
    for (int i = 0; i < 4; ++i) {
        mx[i] = BIGF; ms[i] = 0;
#pragma unroll
        for (int j = 0; j < KNN; ++j) { tv[i][j] = BIGF; tix[i][j] = 0; }
    }

    for (int t = 0; t < TILES_PER_SPLIT; ++t) {
        const int colbase = colbase0 + t * BM;
        __syncthreads();  // prev tile's Ms reads complete before overwrite
        {
            const float* gm = mem + (size_t)colbase * DIM;
#pragma unroll
            for (int it = 0; it < 8; ++it) {
                int flat = tid + NTHREADS * it;
                int r = flat >> 5;
                int c4 = flat & 31;
                float4 v = reinterpret_cast<const float4*>(gm + (size_t)r * DIM)[c4];
                int g = r >> 2, rl = r & 3;
                int d0 = c4 << 2;
                Ms[(d0 + 0) * 64 + ((g ^ ((d0 + 0) & 15)) << 2) + rl] = v.x;
                Ms[(d0 + 1) * 64 + ((g ^ ((d0 + 1) & 15)) << 2) + rl] = v.y;
                Ms[(d0 + 2) * 64 + ((g ^ ((d0 + 2) & 15)) << 2) + rl] = v.z;
                Ms[(d0 + 3) * 64 + ((g ^ ((d0 + 3) & 15)) << 2) + rl] = v.w;
            }
            if (tid < 16) {
                reinterpret_cast<float4*>(m2s)[tid] =
                    reinterpret_cast<const float4*>(m2 + colbase)[tid];
            }
        }
        __syncthreads();

        float acc[4][4];
#pragma unroll
        for (int i = 0; i < 4; ++i)
#pragma unroll
            for (int j = 0; j < 4; ++j) acc[i][j] = 0.f;

#pragma unroll 16
        for (int k = 0; k < DIM; ++k) {
            float4 a = *reinterpret_cast<const float4*>(
                &Qs[k * 64 + ((ty ^ (k & 15)) << 2)]);
            float4 b = *reinterpret_cast<const float4*>(
                &Ms[k * 64 + ((tx ^ (k & 15)) << 2)]);
            acc[0][0] = fmaf(a.x, b.x, acc[0][0]);
            acc[0][1] = fmaf(a.x, b.y, acc[0][1]);
            acc[0][2] = fmaf(a.x, b.z, acc[0][2]);
            acc[0][3] = fmaf(a.x, b.w, acc[0][3]);
            acc[1][0] = fmaf(a.y, b.x, acc[1][0]);
            acc[1][1] = fmaf(a.y, b.y, acc[1][1]);
            acc[1][2] = fmaf(a.y, b.z, acc[1][2]);
            acc[1][3] = fmaf(a.y, b.w, acc[1][3]);
            acc[2][0] = fmaf(a.z, b.x, acc[2][0]);
            acc[2][1] = fmaf(a.z, b.y, acc[2][1]);
            acc[2][2] = fmaf(a.z, b.z, acc[2][2]);
            acc[2][3] = fmaf(a.z, b.w, acc[2][3]);
            acc[3][0] = fmaf(a.w, b.x, acc[3][0]);
            acc[3][1] = fmaf(a.w, b.y, acc[3][1]);
            acc[3][2] = fmaf(a.w, b.z, acc[3][2]);
            acc[3][3] = fmaf(a.w, b.w, acc[3][3]);
        }

        // ---- top-5 update (ranking key s = m2 - 2*dot; q2 added later) ----
#pragma unroll
        for (int j = 0; j < 4; ++j) {
            int col = colbase + (tx << 2) + j;
            float m2v = m2s[(tx << 2) + j];
#pragma unroll
            for (int i = 0; i < 4; ++i) {
                float s = fmaf(-2.f, acc[i][j], m2v);
                if (s < mx[i]) {
#pragma unroll
                    for (int t5 = 0; t5 < KNN; ++t5)
                        if (t5 == ms[i]) { tv[i][t5] = s; tix[i][t5] = col; }
                    float nm = tv[i][0]; int na = 0;
#pragma unroll
                    for (int t5 = 1; t5 < KNN; ++t5)
                        if (tv[i][t5] > nm) { nm = tv[i][t5]; na = t5; }
                    mx[i] = nm; ms[i] = na;
                }
            }
        }
    }

    // ---- merge 16 per-thread lists per row through LDS (reuse tile LDS) ----
    __syncthreads();
    float* cv = lds;                                  // [64][80] floats
    int*   ci = reinterpret_cast<int*>(lds + 5120);   // [64][80] ints
#pragma unroll
    for (int i = 0; i < 4; ++i) {
        int r = (ty << 2) + i;
#pragma unroll
        for (int j = 0; j < KNN; ++j) {
            cv[r * 80 + tx * KNN + j] = tv[i][j];
            ci[r * 80 + tx * KNN + j] = tix[i][j];
        }
    }
    __syncthreads();
    if (tid < BN) {
        const float* rv = cv + tid * 80;
        const int*   ri = ci + tid * 80;
        float bv[KNN]; int bi[KNN];
#pragma unroll
        for (int j = 0; j < KNN; ++j) { bv[j] = rv[j]; bi[j] = ri[j]; }
        float bmx = bv[0]; int bms = 0;
#pragma unroll
        for (int j = 1; j < KNN; ++j)
            if (bv[j] > bmx) { bmx = bv[j]; bms = j; }
        for (int c = KNN; c < 16 * KNN; ++c) {
            float v = rv[c];
            if (v < bmx) {
                int ix = ri[c];
#pragma unroll
                for (int t5 = 0; t5 < KNN; ++t5)
                    if (t5 == bms) { bv[t5] = v; bi[t5] = ix; }
                float nm = bv[0]; int na = 0;
#pragma unroll
                for (int t5 = 1; t5 < KNN; ++t5)
                    if (bv[t5] > nm) { nm = bv[t5]; na = t5; }
                bmx = nm; bms = na;
            }
        }
        size_t base = ((size_t)(row0 + tid) * SPLITS + blockIdx.y) * KNN;
#pragma unroll
        for (int j = 0; j < KNN; ++j) {
            candV[base + j] = bv[j];
            candI[base + j] = bi[j];
        }
    }
}

// ---------------------------------------------------------------------------
// Kernel 3: per query merge SPLITS*5 candidates -> top5, then the adaptive
// KNN reduction (softmax-weighted distance / neighbor scale * consistency).
// ---------------------------------------------------------------------------
__global__ void finalize_kernel(const float* __restrict__ q2,
                                const float* __restrict__ candV,
                                const int* __restrict__ candI,
                                const float* __restrict__ scaleb,
                                float* __restrict__ out) {
    int n = blockIdx.x * blockDim.x + threadIdx.x;
    if (n >= N_Q) return;
    float q2v = q2[n];
    const float* cv = candV + (size_t)n * (SPLITS * KNN);
    const int*   ci = candI + (size_t)n * (SPLITS * KNN);
    float bv[KNN]; int bi[KNN];
#pragma unroll
    for (int j = 0; j < KNN; ++j) { bv[j] = cv[j]; bi[j] = ci[j]; }
    float bmx = bv[0]; int bms = 0;
#pragma unroll
    for (int j = 1; j < KNN; ++j)
        if (bv[j] > bmx) { bmx = bv[j]; bms = j; }
#pragma unroll
    for (int c = KNN; c < SPLITS * KNN; ++c) {
        float v = cv[c];
        if (v < bmx) {
            int ix = ci[c];
#pragma unroll
            for (int t5 = 0; t5 < KNN; ++t5)
                if (t5 == bms) { bv[t5] = v; bi[t5] = ix; }
            float nm = bv[0]; int na = 0;
#pragma unroll
            for (int t5 = 1; t5 < KNN; ++t5)
                if (bv[t5] > nm) { nm = bv[t5]; na = t5; }
            bmx = nm; bms = na;
        }
    }
    // distances
    float d[KNN];
    float dmin = BIGF;
#pragma unroll
    for (int j = 0; j < KNN; ++j) {
        d[j] = sqrtf(fmaxf(q2v + bv[j], 1e-12f));
        dmin = fminf(dmin, d[j]);
    }
    float se = 0.f, wd = 0.f, sm = 0.f, ssc = 0.f;
#pragma unroll
    for (int j = 0; j < KNN; ++j) {
        float e = expf(-(d[j] - dmin));  // softmax(-d), stable
        se += e;
        wd = fmaf(e, d[j], wd);
        sm += d[j];
        ssc += scaleb[bi[j]];
    }
    wd /= se;
    float scale = ssc * 0.2f;
    float nd = wd / fmaxf(scale, 1e-6f);
    float mean = sm * 0.2f;
    float var = 0.f;
#pragma unroll
    for (int j = 0; j < KNN; ++j) {
        float dd = d[j] - mean;
        var = fmaf(dd, dd, var);
    }
    var *= 0.2f;
    float cons = sqrtf(var) / fmaxf(mean, 1e-6f);
    out[n] = nd * (1.f + 0.5f * cons);
}

// ---------------------------------------------------------------------------
// ws layout (floats): q2[N] | m2[M] | candV[N*SPLITS*KNN] | candI (ints)
// total = 16384*2 + 163840*2 floats = ~1.4 MB
// ---------------------------------------------------------------------------
extern "C" void kernel_launch(void* const* d_in, const int* in_sizes, int n_in,
                              void* d_out, int out_size, void* d_ws,
                              size_t ws_size, hipStream_t stream) {
    const float* query  = (const float*)d_in[0];
    const float* mem    = (const float*)d_in[1];
    const float* scaleb = (const float*)d_in[2];
    // d_in[3] is k==5, compile-time constant here.
    float* out = (float*)d_out;

    float* ws = (float*)d_ws;
    float* q2 = ws;
    float* m2 = ws + N_Q;
    float* candV = ws + N_Q + N_M;
    int*   candI = (int*)(candV + (size_t)N_Q * SPLITS * KNN);

    row_sumsq_kernel<<<(N_Q + N_M) / 4, 256, 0, stream>>>(query, mem, q2, m2);
    dim3 grid(N_Q / BN, SPLITS);
    knn_main_kernel<<<grid, NTHREADS, 0, stream>>>(query, mem, m2, candV, candI);
    finalize_kernel<<<N_Q / 256, 256, 0, stream>>>(q2, candV, candI, scaleb, out);
}

// Round 2
// 778.956 us; speedup vs baseline: 2.1866x; 2.1866x over previous
//
#include <hip/hip_runtime.h>
#include <hip/hip_bf16.h>
#include <math.h>

#define N_Q 16384
#define N_M 16384
#define DIM 128
#define KNN 5
#define SPLITS 4
#define COLS_PER_SPLIT (N_M / SPLITS)   // 4096
#define ITERS (COLS_PER_SPLIT / 128)    // 32
#define TSEL 16                         // candidates kept per (row, split)
#define LLIST 8                         // per-lane running list length
#define BIGF 3.0e38f

typedef __bf16 bf16x8 __attribute__((ext_vector_type(8)));
typedef float f32x4 __attribute__((ext_vector_type(4)));

// ---------------------------------------------------------------------------
// Kernel A: per-row sumsq (fp32) + bf16 conversion of query and memory bank.
// One wave per row.
// ---------------------------------------------------------------------------
__global__ void prep_kernel(const float* __restrict__ q,
                            const float* __restrict__ mem,
                            float* __restrict__ q2, float* __restrict__ m2,
                            __hip_bfloat16* __restrict__ qb,
                            __hip_bfloat16* __restrict__ mb) {
    int gt = blockIdx.x * blockDim.x + threadIdx.x;
    int wid = gt >> 6;
    int lane = gt & 63;
    const float* src;
    float* dst;
    __hip_bfloat16* bdst;
    if (wid < N_Q) {
        src = q + (size_t)wid * DIM;
        dst = q2 + wid;
        bdst = qb + (size_t)wid * DIM;
    } else {
        int r = wid - N_Q;
        src = mem + (size_t)r * DIM;
        dst = m2 + r;
        bdst = mb + (size_t)r * DIM;
    }
    float2 v = reinterpret_cast<const float2*>(src)[lane];
    __hip_bfloat162 bv;
    bv.x = __float2bfloat16(v.x);
    bv.y = __float2bfloat16(v.y);
    reinterpret_cast<__hip_bfloat162*>(bdst)[lane] = bv;
    float s = fmaf(v.x, v.x, v.y * v.y);
#pragma unroll
    for (int off = 32; off > 0; off >>= 1) s += __shfl_down(s, off, 64);
    if (lane == 0) *dst = s;
}

// ---------------------------------------------------------------------------
// Kernel B: bf16 MFMA scoring GEMM fused with per-row top selection.
// Block: 256 threads = 4 waves; tile 64 rows x 128 cols; full K=128.
// Wave w owns rows w*16..w*16+15 (A-fragments in registers, loaded once).
// M tile (128 cols x 128 k, bf16 = 32 KB) staged to LDS each iteration in
// XOR-swizzled 16B granules: granule (c,gk) stored at slot
//   sg = (gk&8) | ((gk^c)&7)   -> ds_read_b128 fragment reads and the staging
// ds_write_b128 both spread uniformly (8 addrs per 4-bank group = b128 min).
// Score s = m2[col] - 2*dot ranks identically to d^2 (q2 is row-constant).
// Each lane keeps top-8 (val,idx) for its 4 C-rows over its 8-col stripe;
// end-of-kernel: shuffle pair-merge (16 lanes -> 8 per row), LDS dump,
// per-row scan -> top-16 indices -> candI[(row*SPLITS + split)*16 + j].
// ---------------------------------------------------------------------------
__global__ __launch_bounds__(256, 3) void knn_tops_kernel(
    const __hip_bfloat16* __restrict__ qb, const __hip_bfloat16* __restrict__ mb,
    const float* __restrict__ m2, int* __restrict__ candI) {
    __shared__ __align__(16) unsigned char smem[33280];
    float* m2s = (float*)(smem + 32768);      // 512 B, live during main loop
    float* MGv = (float*)smem;                 // merge overlay: [64][65] floats
    int*   MGi = (int*)(smem + 16640);         // merge overlay: [64][65] ints

    const int tid = threadIdx.x;
    const int w = tid >> 6;      // wave 0..3
    const int lane = tid & 63;
    const int i16 = lane & 15;   // C col within 16x16 tile / A,B row index
    const int g = lane >> 4;     // k-granule group 0..3
    const int row0 = blockIdx.x * 64;
    const int col0 = blockIdx.y * COLS_PER_SPLIT;

    // ---- A fragments: 4 k-steps, from global bf16, once ----
    bf16x8 afrag[4];
    {
        const __hip_bfloat16* qrow = qb + (size_t)(row0 + w * 16 + i16) * DIM;
#pragma unroll
        for (int ks = 0; ks < 4; ++ks)
            afrag[ks] = *reinterpret_cast<const bf16x8*>(qrow + ks * 32 + g * 8);
    }

    // ---- per-lane top-8 lists for 4 rows ----
    float tv[4][LLIST];
    int   tix[4][LLIST];
    float mx[4];
    int   ms[4];
#pragma unroll
    for (int r = 0; r < 4; ++r) {
        mx[r] = BIGF; ms[r] = 0;
#pragma unroll
        for (int j = 0; j < LLIST; ++j) { tv[r][j] = BIGF; tix[r][j] = 0; }
    }

    for (int t = 0; t < ITERS; ++t) {
        const int colbase = col0 + t * 128;
        // stage M tile: 2048 granules of 16B; 8 per thread.
        uint4 stg[8];
#pragma unroll
        for (int it = 0; it < 8; ++it) {
            int fg = tid + 256 * it;       // LDS granule slot
            int c = fg >> 4, sg = fg & 15;
            int gk = (sg & 8) | ((sg ^ c) & 7);   // unswizzle -> source granule
            stg[it] = *reinterpret_cast<const uint4*>(
                mb + (size_t)(colbase + c) * DIM + gk * 8);
        }
        __syncthreads();  // prior iteration's fragment reads complete
#pragma unroll
        for (int it = 0; it < 8; ++it) {
            int fg = tid + 256 * it;
            *reinterpret_cast<uint4*>(smem + fg * 16) = stg[it];
        }
        if (tid < 32)
            reinterpret_cast<float4*>(m2s)[tid] =
                reinterpret_cast<const float4*>(m2 + colbase)[tid];
        __syncthreads();

        // ---- MFMA: 8 col-tiles x 4 k-steps ----
        f32x4 acc[8];
#pragma unroll
        for (int ct = 0; ct < 8; ++ct) acc[ct] = (f32x4){0.f, 0.f, 0.f, 0.f};
#pragma unroll
        for (int ks = 0; ks < 4; ++ks) {
#pragma unroll
            for (int ct = 0; ct < 8; ++ct) {
                int c = ct * 16 + i16;
                int gk = g + ks * 4;
                int sg = (gk & 8) | ((gk ^ c) & 7);
                bf16x8 bfr = *reinterpret_cast<const bf16x8*>(smem + c * 256 + sg * 16);
                acc[ct] = __builtin_amdgcn_mfma_f32_16x16x32_bf16(
                    afrag[ks], bfr, acc[ct], 0, 0, 0);
            }
        }

        float m2v[8];
#pragma unroll
        for (int ct = 0; ct < 8; ++ct) m2v[ct] = m2s[ct * 16 + i16];

        // ---- selection epilogue: lane's rows are g*4+r, cols ct*16+i16 ----
#pragma unroll
        for (int r = 0; r < 4; ++r) {
            float sv[8];
#pragma unroll
            for (int ct = 0; ct < 8; ++ct)
                sv[ct] = fmaf(-2.f, acc[ct][r], m2v[ct]);
            float mn = fminf(fminf(fminf(sv[0], sv[1]), fminf(sv[2], sv[3])),
                             fminf(fminf(sv[4], sv[5]), fminf(sv[6], sv[7])));
            if (mn < mx[r]) {
#pragma unroll
                for (int ct = 0; ct < 8; ++ct) {
                    if (sv[ct] < mx[r]) {
                        int col = colbase + ct * 16 + i16;
#pragma unroll
                        for (int j = 0; j < LLIST; ++j)
                            if (j == ms[r]) { tv[r][j] = sv[ct]; tix[r][j] = col; }
                        float nm = tv[r][0]; int na = 0;
#pragma unroll
                        for (int j = 1; j < LLIST; ++j)
                            if (tv[r][j] > nm) { nm = tv[r][j]; na = j; }
                        mx[r] = nm; ms[r] = na;
                    }
                }
            }
        }
    }

    __syncthreads();  // M-tile LDS no longer needed; safe to overlay

    // ---- phase 1: merge lane i with lane i^8 (same rows), keep in i<8 ----
#pragma unroll
    for (int r = 0; r < 4; ++r) {
#pragma unroll
        for (int j = 0; j < LLIST; ++j) {
            float pv = __shfl_xor(tv[r][j], 8, 64);
            int   pi = __shfl_xor(tix[r][j], 8, 64);
            if (i16 < 8 && pv < mx[r]) {
#pragma unroll
                for (int q = 0; q < LLIST; ++q)
                    if (q == ms[r]) { tv[r][q] = pv; tix[r][q] = pi; }
                float nm = tv[r][0]; int na = 0;
#pragma unroll
                for (int q = 1; q < LLIST; ++q)
                    if (tv[r][q] > nm) { nm = tv[r][q]; na = q; }
                mx[r] = nm; ms[r] = na;
            }
        }
    }
    // ---- dump: 8 lanes x 8 entries per row, padded stride 65 ----
    if (i16 < 8) {
#pragma unroll
        for (int r = 0; r < 4; ++r) {
            int row = w * 16 + g * 4 + r;
#pragma unroll
            for (int j = 0; j < LLIST; ++j) {
                MGv[row * 65 + i16 * LLIST + j] = tv[r][j];
                MGi[row * 65 + i16 * LLIST + j] = tix[r][j];
            }
        }
    }
    __syncthreads();
    // ---- phase 2: one thread per row scans 64 entries -> top-16 indices ----
    if (tid < 64) {
        float bv[TSEL]; int bi[TSEL];
#pragma unroll
        for (int j = 0; j < TSEL; ++j) { bv[j] = BIGF; bi[j] = 0; }
        float bmx = BIGF; int bms = 0;
        for (int c = 0; c < 64; ++c) {
            float v = MGv[tid * 65 + c];
            if (v < bmx) {
                int ix = MGi[tid * 65 + c];
#pragma unroll
                for (int j = 0; j < TSEL; ++j)
                    if (j == bms) { bv[j] = v; bi[j] = ix; }
                float nm = bv[0]; int na = 0;
#pragma unroll
                for (int j = 1; j < TSEL; ++j)
                    if (bv[j] > nm) { nm = bv[j]; na = j; }
                bmx = nm; bms = na;
            }
        }
        size_t base = ((size_t)(row0 + tid) * SPLITS + blockIdx.y) * TSEL;
#pragma unroll
        for (int j = 0; j < TSEL; ++j) candI[base + j] = bi[j];
    }
}

// ---------------------------------------------------------------------------
// Kernel C: exact fp32 re-rank of 64 candidates/query + adaptive-KNN output.
// One wave per query; lane = one candidate. d2 = q2 + m2 - 2*dot (fp32,
// original inputs). 5 extraction rounds of shuffle-argmin -> exact top-5.
// ---------------------------------------------------------------------------
__global__ __launch_bounds__(256) void finalize_kernel(
    const float* __restrict__ q, const float* __restrict__ mem,
    const float* __restrict__ q2, const float* __restrict__ m2,
    const int* __restrict__ candI, const float* __restrict__ scaleb,
    float* __restrict__ out) {
    int wv = threadIdx.x >> 6, lane = threadIdx.x & 63;
    int n = blockIdx.x * 4 + wv;
    int ci = candI[(size_t)n * 64 + lane];
    const float4* qr = reinterpret_cast<const float4*>(q + (size_t)n * DIM);
    const float4* mr = reinterpret_cast<const float4*>(mem + (size_t)ci * DIM);
    float dot = 0.f;
#pragma unroll
    for (int k = 0; k < 32; ++k) {
        float4 a = qr[k], b = mr[k];
        dot = fmaf(a.x, b.x, fmaf(a.y, b.y, fmaf(a.z, b.z, fmaf(a.w, b.w, dot))));
    }
    float v = q2[n] + m2[ci] - 2.f * dot;

    float dk[KNN]; int ik[KNN];
#pragma unroll
    for (int r = 0; r < KNN; ++r) {
        float mv = v; int ml = lane;
#pragma unroll
        for (int off = 32; off > 0; off >>= 1) {
            float ov = __shfl_xor(mv, off, 64);
            int   ol = __shfl_xor(ml, off, 64);
            if (ov < mv || (ov == mv && ol < ml)) { mv = ov; ml = ol; }
        }
        dk[r] = sqrtf(fmaxf(mv, 1e-12f));
        ik[r] = __shfl(ci, ml, 64);
        if (lane == ml) v = BIGF;
    }
    if (lane == 0) {
        float dmin = dk[0];
        float se = 0.f, wd = 0.f, sm = 0.f, ssc = 0.f;
#pragma unroll
        for (int j = 0; j < KNN; ++j) {
            float e = expf(-(dk[j] - dmin));
            se += e;
            wd = fmaf(e, dk[j], wd);
            sm += dk[j];
            ssc += scaleb[ik[j]];
        }
        wd /= se;
        float scale = ssc * 0.2f;
        float nd = wd / fmaxf(scale, 1e-6f);
        float mean = sm * 0.2f;
        float var = 0.f;
#pragma unroll
        for (int j = 0; j < KNN; ++j) {
            float dd = dk[j] - mean;
            var = fmaf(dd, dd, var);
        }
        var *= 0.2f;
        float cons = sqrtf(var) / fmaxf(mean, 1e-6f);
        out[n] = nd * (1.f + 0.5f * cons);
    }
}

// ---------------------------------------------------------------------------
// ws layout: q2[N] f32 | m2[M] f32 | qb[N*128] bf16 | mb[M*128] bf16 |
//            candI[N*SPLITS*16] int  (~12.4 MB total)
// ---------------------------------------------------------------------------
extern "C" void kernel_launch(void* const* d_in, const int* in_sizes, int n_in,
                              void* d_out, int out_size, void* d_ws,
                              size_t ws_size, hipStream_t stream) {
    const float* query  = (const float*)d_in[0];
    const float* mem    = (const float*)d_in[1];
    const float* scaleb = (const float*)d_in[2];
    float* out = (float*)d_out;

    float* q2 = (float*)d_ws;
    float* m2 = q2 + N_Q;
    __hip_bfloat16* qb = (__hip_bfloat16*)(m2 + N_M);
    __hip_bfloat16* mb = qb + (size_t)N_Q * DIM;
    int* candI = (int*)(mb + (size_t)N_M * DIM);

    prep_kernel<<<(N_Q + N_M) / 4, 256, 0, stream>>>(query, mem, q2, m2, qb, mb);
    dim3 gridB(N_Q / 64, SPLITS);
    knn_tops_kernel<<<gridB, 256, 0, stream>>>(qb, mb, m2, candI);
    finalize_kernel<<<N_Q / 4, 256, 0, stream>>>(query, mem, q2, m2, candI,
                                                 scaleb, out);
}

// Round 3
// 679.337 us; speedup vs baseline: 2.5073x; 1.1466x over previous
//
#include <hip/hip_runtime.h>
#include <hip/hip_bf16.h>
#include <math.h>

#define N_Q 16384
#define N_M 16384
#define DIM 128
#define KNN 5
#define SPLITS 4
#define COLS_PER_SPLIT (N_M / SPLITS)   // 4096
#define ITERS (COLS_PER_SPLIT / 128)    // 32
#define BROWS 128                        // rows per block (4 waves x 32)
#define TSEL 8                           // candidates kept per (row, split)
#define LLIST 5                          // per-lane running list length
#define BIGF 3.0e38f

typedef __bf16 bf16x8 __attribute__((ext_vector_type(8)));
typedef float f32x4 __attribute__((ext_vector_type(4)));

// async global->LDS, 16B per lane; LDS dest = wave-uniform base + lane*16
__device__ __forceinline__ void gl2lds16(const void* g, void* l) {
    __builtin_amdgcn_global_load_lds(
        (const __attribute__((address_space(1))) void*)g,
        (__attribute__((address_space(3))) void*)l, 16, 0, 0);
}

// ---------------------------------------------------------------------------
// Kernel A: per-row sumsq (fp32) + bf16 conversion. One wave per row.
// ---------------------------------------------------------------------------
__global__ void prep_kernel(const float* __restrict__ q,
                            const float* __restrict__ mem,
                            float* __restrict__ q2, float* __restrict__ m2,
                            __hip_bfloat16* __restrict__ qb,
                            __hip_bfloat16* __restrict__ mb) {
    int gt = blockIdx.x * blockDim.x + threadIdx.x;
    int wid = gt >> 6;
    int lane = gt & 63;
    const float* src;
    float* dst;
    __hip_bfloat16* bdst;
    if (wid < N_Q) {
        src = q + (size_t)wid * DIM;
        dst = q2 + wid;
        bdst = qb + (size_t)wid * DIM;
    } else {
        int r = wid - N_Q;
        src = mem + (size_t)r * DIM;
        dst = m2 + r;
        bdst = mb + (size_t)r * DIM;
    }
    float2 v = reinterpret_cast<const float2*>(src)[lane];
    __hip_bfloat162 bv;
    bv.x = __float2bfloat16(v.x);
    bv.y = __float2bfloat16(v.y);
    reinterpret_cast<__hip_bfloat162*>(bdst)[lane] = bv;
    float s = fmaf(v.x, v.x, v.y * v.y);
#pragma unroll
    for (int off = 32; off > 0; off >>= 1) s += __shfl_down(s, off, 64);
    if (lane == 0) *dst = s;
}

// ---------------------------------------------------------------------------
// Kernel B: bf16 MFMA scoring + per-row top selection with PACKED keys.
// Block: 256 threads = 4 waves; tile 128 rows x 128 cols; full K=128.
// Wave w owns rows [w*32, w*32+32) as TWO 16-row MFMA tiles -> each B-frag
// ds_read_b128 feeds 2 MFMAs (halves LDS read traffic vs 1 tile/wave).
// M tile (128 cols x 128 k bf16 = 32 KB) staged via global_load_lds(16B) in
// XOR-swizzled granules: slot sg = (gk&8)|((gk^c)&7) -> conflict-free b128
// fragment reads; staging order is lane-contiguous by construction.
// Score s = m2[col] - 2*dot packed as: flip(fp32 bits) & ~16383 | col
//   -> single-uint min-order == score order, index rides along free.
// Per-lane 5-deep lists for 8 rows; shuffle pair-merge; LDS scan -> top-8
// per (row, split) -> candI.
// ---------------------------------------------------------------------------
__global__ __launch_bounds__(256, 2) void knn_tops_kernel(
    const __hip_bfloat16* __restrict__ qb, const __hip_bfloat16* __restrict__ mb,
    const float* __restrict__ m2, int* __restrict__ candI) {
    __shared__ __align__(16) unsigned char smem[33280];  // 32KB tile + 512B m2s
    const int tid = threadIdx.x;
    const int w = tid >> 6;
    const int lane = tid & 63;
    const int i16 = lane & 15;
    const int g = lane >> 4;
    const int row0 = blockIdx.x * BROWS;
    const int col0 = blockIdx.y * COLS_PER_SPLIT;

    // ---- A fragments for 2 row-tiles x 4 k-steps (loaded once) ----
    bf16x8 afrag[2][4];
#pragma unroll
    for (int ti = 0; ti < 2; ++ti) {
        const __hip_bfloat16* qrow =
            qb + (size_t)(row0 + w * 32 + ti * 16 + i16) * DIM;
#pragma unroll
        for (int ks = 0; ks < 4; ++ks)
            afrag[ti][ks] = *reinterpret_cast<const bf16x8*>(qrow + ks * 32 + g * 8);
    }

    // ---- packed-key lists: 8 rows x 5 ----
    unsigned lst[8][LLIST];
    unsigned mxv[8];
    int mxs[8];
#pragma unroll
    for (int rr = 0; rr < 8; ++rr) {
        mxv[rr] = 0xFFFFFFFFu; mxs[rr] = 0;
#pragma unroll
        for (int j = 0; j < LLIST; ++j) lst[rr][j] = 0xFFFFFFFFu;
    }

    auto insert = [&](int rr, unsigned key) {
#pragma unroll
        for (int j = 0; j < LLIST; ++j)
            if (j == mxs[rr]) lst[rr][j] = key;
        unsigned nm = lst[rr][0]; int na = 0;
#pragma unroll
        for (int j = 1; j < LLIST; ++j)
            if (lst[rr][j] > nm) { nm = lst[rr][j]; na = j; }
        mxv[rr] = nm; mxs[rr] = na;
    };

    // per-thread staging geometry (loop-invariant)
    const int fg0 = w * 8 * 64 + lane;  // first granule slot for it=0

    for (int t = 0; t < ITERS; ++t) {
        const int colbase = col0 + t * 128;
        __syncthreads();  // all waves done reading previous tile
        // ---- async stage M tile: 8 issues/thread, 16B each ----
#pragma unroll
        for (int it = 0; it < 8; ++it) {
            int fg = fg0 + it * 64;
            int c = fg >> 4, sg = fg & 15;
            int gk = (sg & 8) | ((sg ^ c) & 7);  // source granule for this slot
            gl2lds16(mb + (size_t)(colbase + c) * DIM + gk * 8,
                     smem + (size_t)fg * 16);
        }
        if (tid < 32) {  // m2 slice: 512B, synchronous (tiny)
            float4 v = *reinterpret_cast<const float4*>(m2 + colbase + tid * 4);
            *reinterpret_cast<float4*>(smem + 32768 + tid * 16) = v;
        }
        __syncthreads();  // vmcnt+lgkm drained by compiler before barrier

        // ---- MFMA: 4 k-steps x 8 col-tiles, B-frag shared by 2 row-tiles ----
        f32x4 acc[2][8];
#pragma unroll
        for (int ti = 0; ti < 2; ++ti)
#pragma unroll
            for (int ct = 0; ct < 8; ++ct) acc[ti][ct] = (f32x4){0.f, 0.f, 0.f, 0.f};
#pragma unroll
        for (int ks = 0; ks < 4; ++ks) {
#pragma unroll
            for (int ct = 0; ct < 8; ++ct) {
                int c = ct * 16 + i16;
                int gk = ks * 4 + g;
                int sg = (gk & 8) | ((gk ^ c) & 7);
                bf16x8 bfr =
                    *reinterpret_cast<const bf16x8*>(smem + c * 256 + sg * 16);
                acc[0][ct] = __builtin_amdgcn_mfma_f32_16x16x32_bf16(
                    afrag[0][ks], bfr, acc[0][ct], 0, 0, 0);
                acc[1][ct] = __builtin_amdgcn_mfma_f32_16x16x32_bf16(
                    afrag[1][ks], bfr, acc[1][ct], 0, 0, 0);
            }
        }

        // ---- selection epilogue (packed keys) ----
        const float* m2f = (const float*)(smem + 32768);
        float m2v[8];
#pragma unroll
        for (int ct = 0; ct < 8; ++ct) m2v[ct] = m2f[ct * 16 + i16];
#pragma unroll
        for (int ti = 0; ti < 2; ++ti) {
#pragma unroll
            for (int r = 0; r < 4; ++r) {
                const int rr = ti * 4 + r;
                unsigned key[8];
                unsigned kmin = 0xFFFFFFFFu;
#pragma unroll
                for (int ct = 0; ct < 8; ++ct) {
                    float s = fmaf(-2.f, acc[ti][ct][r], m2v[ct]);
                    unsigned u = __float_as_uint(s);
                    unsigned k = u ^ ((unsigned)((int)u >> 31) | 0x80000000u);
                    k = (k & 0xFFFFC000u) | (unsigned)(colbase + ct * 16 + i16);
                    key[ct] = k;
                    kmin = min(kmin, k);
                }
                if (kmin < mxv[rr]) {
#pragma unroll
                    for (int ct = 0; ct < 8; ++ct)
                        if (key[ct] < mxv[rr]) insert(rr, key[ct]);
                }
            }
        }
    }

    __syncthreads();  // tile LDS dead; safe to overlay merge buffer

    // ---- phase 1: merge lane i16 with i16^8 (same rows), keep in i16<8 ----
#pragma unroll
    for (int rr = 0; rr < 8; ++rr) {
#pragma unroll
        for (int j = 0; j < LLIST; ++j) {
            unsigned pv = (unsigned)__shfl_xor((int)lst[rr][j], 8, 64);
            if (i16 < 8 && pv < mxv[rr]) insert(rr, pv);
        }
    }
    // ---- dump: 8 lanes x 5 keys per row, stride 41 (odd -> 2-way max) ----
    unsigned* MG = (unsigned*)smem;  // [128][41]
    if (i16 < 8) {
#pragma unroll
        for (int rr = 0; rr < 8; ++rr) {
            int row = w * 32 + (rr >> 2) * 16 + g * 4 + (rr & 3);
#pragma unroll
            for (int j = 0; j < LLIST; ++j)
                MG[row * 41 + i16 * LLIST + j] = lst[rr][j];
        }
    }
    __syncthreads();
    // ---- phase 2: thread per row scans 40 keys -> top-8 -> candI ----
    if (tid < BROWS) {
        unsigned bk[TSEL];
        unsigned bmx = 0xFFFFFFFFu; int bms = 0;
#pragma unroll
        for (int j = 0; j < TSEL; ++j) bk[j] = 0xFFFFFFFFu;
        for (int c = 0; c < 8 * LLIST; ++c) {
            unsigned v = MG[tid * 41 + c];
            if (v < bmx) {
#pragma unroll
                for (int j = 0; j < TSEL; ++j)
                    if (j == bms) bk[j] = v;
                unsigned nm = bk[0]; int na = 0;
#pragma unroll
                for (int j = 1; j < TSEL; ++j)
                    if (bk[j] > nm) { nm = bk[j]; na = j; }
                bmx = nm; bms = na;
            }
        }
        size_t base = ((size_t)(row0 + tid) * SPLITS + blockIdx.y) * TSEL;
#pragma unroll
        for (int j = 0; j < TSEL; ++j) candI[base + j] = (int)(bk[j] & 16383u);
    }
}

// ---------------------------------------------------------------------------
// Kernel C: exact fp32 re-rank of 32 candidates/query + adaptive-KNN output.
// One wave per query. Lane (c, half): lanes 0-31 = candidates, halves split
// the 128-dim dot (64 dims each), pair-summed via shfl_xor(32).
// ---------------------------------------------------------------------------
__global__ __launch_bounds__(256) void finalize_kernel(
    const float* __restrict__ q, const float* __restrict__ mem,
    const float* __restrict__ q2, const float* __restrict__ m2,
    const int* __restrict__ candI, const float* __restrict__ scaleb,
    float* __restrict__ out) {
    int wv = threadIdx.x >> 6, lane = threadIdx.x & 63;
    int n = blockIdx.x * 4 + wv;
    int cl = lane & 31, half = lane >> 5;
    int ci = candI[(size_t)n * 32 + cl];
    const float4* qr =
        reinterpret_cast<const float4*>(q + (size_t)n * DIM) + half * 16;
    const float4* mr =
        reinterpret_cast<const float4*>(mem + (size_t)ci * DIM) + half * 16;
    float dot = 0.f;
#pragma unroll
    for (int k = 0; k < 16; ++k) {
        float4 a = qr[k], b = mr[k];
        dot = fmaf(a.x, b.x, fmaf(a.y, b.y, fmaf(a.z, b.z, fmaf(a.w, b.w, dot))));
    }
    dot += __shfl_xor(dot, 32, 64);
    float v = q2[n] + m2[ci] - 2.f * dot;

    float dk[KNN]; int ik[KNN];
#pragma unroll
    for (int r = 0; r < KNN; ++r) {
        float mv = v; int ml = lane;
#pragma unroll
        for (int off = 32; off > 0; off >>= 1) {
            float ov = __shfl_xor(mv, off, 64);
            int   ol = __shfl_xor(ml, off, 64);
            if (ov < mv || (ov == mv && ol < ml)) { mv = ov; ml = ol; }
        }
        dk[r] = sqrtf(fmaxf(mv, 1e-12f));
        ik[r] = __shfl(ci, ml, 64);
        if ((lane & 31) == (ml & 31)) v = BIGF;  // kill BOTH half-copies
    }
    if (lane == 0) {
        float dmin = dk[0];
        float se = 0.f, wd = 0.f, sm = 0.f, ssc = 0.f;
#pragma unroll
        for (int j = 0; j < KNN; ++j) {
            float e = expf(-(dk[j] - dmin));
            se += e;
            wd = fmaf(e, dk[j], wd);
            sm += dk[j];
            ssc += scaleb[ik[j]];
        }
        wd /= se;
        float scale = ssc * 0.2f;
        float nd = wd / fmaxf(scale, 1e-6f);
        float mean = sm * 0.2f;
        float var = 0.f;
#pragma unroll
        for (int j = 0; j < KNN; ++j) {
            float dd = dk[j] - mean;
            var = fmaf(dd, dd, var);
        }
        var *= 0.2f;
        float cons = sqrtf(var) / fmaxf(mean, 1e-6f);
        out[n] = nd * (1.f + 0.5f * cons);
    }
}

// ---------------------------------------------------------------------------
// ws layout: q2[N] f32 | m2[M] f32 | qb bf16 | mb bf16 | candI[N*32] int
// (~10.4 MB)
// ---------------------------------------------------------------------------
extern "C" void kernel_launch(void* const* d_in, const int* in_sizes, int n_in,
                              void* d_out, int out_size, void* d_ws,
                              size_t ws_size, hipStream_t stream) {
    const float* query  = (const float*)d_in[0];
    const float* mem    = (const float*)d_in[1];
    const float* scaleb = (const float*)d_in[2];
    float* out = (float*)d_out;

    float* q2 = (float*)d_ws;
    float* m2 = q2 + N_Q;
    __hip_bfloat16* qb = (__hip_bfloat16*)(m2 + N_M);
    __hip_bfloat16* mb = qb + (size_t)N_Q * DIM;
    int* candI = (int*)(mb + (size_t)N_M * DIM);

    prep_kernel<<<(N_Q + N_M) / 4, 256, 0, stream>>>(query, mem, q2, m2, qb, mb);
    dim3 gridB(N_Q / BROWS, SPLITS);
    knn_tops_kernel<<<gridB, 256, 0, stream>>>(qb, mb, m2, candI);
    finalize_kernel<<<N_Q / 4, 256, 0, stream>>>(query, mem, q2, m2, candI,
                                                 scaleb, out);
}

// Round 5
// 272.524 us; speedup vs baseline: 6.2500x; 2.4928x over previous
//
#include <hip/hip_runtime.h>
#include <hip/hip_bf16.h>
#include <math.h>

#define N_Q 16384
#define N_M 16384
#define DIM 128
#define KNN 5
#define SPLITS 8
#define COLS_PER_SPLIT (N_M / SPLITS)   // 2048
#define ITERS (COLS_PER_SPLIT / 128)    // 16
#define BROWS 128                        // rows per block (4 waves x 32)
#define TSEL 8                           // keys kept per (row, split)
#define TSEL2 16                         // candidates after global merge
#define LLIST 4                          // per-lane sorted list depth
#define BIGF 3.0e38f

typedef __bf16 bf16x8 __attribute__((ext_vector_type(8)));
typedef float f32x4 __attribute__((ext_vector_type(4)));

__device__ __forceinline__ void gl2lds16(const void* g, void* l) {
    __builtin_amdgcn_global_load_lds(
        (const __attribute__((address_space(1))) void*)g,
        (__attribute__((address_space(3))) void*)l, 16, 0, 0);
}

// branchless sorted insert (ascending), depth 4: 7 VALU, chain depth 2.
// Writes descend so every RHS sees pre-insert values.
#define INS4(L, k)                          \
    do {                                    \
        L[3] = max(L[2], min(L[3], (k)));   \
        L[2] = max(L[1], min(L[2], (k)));   \
        L[1] = max(L[0], min(L[1], (k)));   \
        L[0] = min(L[0], (k));              \
    } while (0)

// ---------------------------------------------------------------------------
// Kernel A: per-row sumsq (fp32) + bf16 conversion. One wave per row.
// ---------------------------------------------------------------------------
__global__ void prep_kernel(const float* __restrict__ q,
                            const float* __restrict__ mem,
                            float* __restrict__ q2, float* __restrict__ m2,
                            __hip_bfloat16* __restrict__ qb,
                            __hip_bfloat16* __restrict__ mb) {
    int gt = blockIdx.x * blockDim.x + threadIdx.x;
    int wid = gt >> 6;
    int lane = gt & 63;
    const float* src;
    float* dst;
    __hip_bfloat16* bdst;
    if (wid < N_Q) {
        src = q + (size_t)wid * DIM;
        dst = q2 + wid;
        bdst = qb + (size_t)wid * DIM;
    } else {
        int r = wid - N_Q;
        src = mem + (size_t)r * DIM;
        dst = m2 + r;
        bdst = mb + (size_t)r * DIM;
    }
    float2 v = reinterpret_cast<const float2*>(src)[lane];
    __hip_bfloat162 bv;
    bv.x = __float2bfloat16(v.x);
    bv.y = __float2bfloat16(v.y);
    reinterpret_cast<__hip_bfloat162*>(bdst)[lane] = bv;
    float s = fmaf(v.x, v.x, v.y * v.y);
#pragma unroll
    for (int off = 32; off > 0; off >>= 1) s += __shfl_down(s, off, 64);
    if (lane == 0) *dst = s;
}

// ---------------------------------------------------------------------------
// Kernel B: bf16 MFMA scoring + branchless per-lane sorted top-4 selection.
// Block 256 = 4 waves; tile 128 rows x 128 cols; K=128; SPLITS=8 col splits.
// Key = asuint(d2) & 0xFFFFC000 | global_col(14b); d2 >= 0 so uint order ==
// score order. Per key: fmaf+add+and_or + 7-op branchless insert.
// XOR-folded LDS addressing: addr(ks,ct,half) =
//   (lds_base ^ (ks<<6)) + half*16384 + ct*4096   (== r3 swizzled layout).
// Phase 1 merges lane pairs i16 <-> i16^8 with SNAPSHOT-then-insert (r4 bug:
// unconditional insert mutated lists while partners were still reading them).
// Phase 2: thread/row scans 32 keys -> top-8 -> candK.
// ---------------------------------------------------------------------------
__global__ __launch_bounds__(256, 3) void knn_tops_kernel(
    const __hip_bfloat16* __restrict__ qb, const __hip_bfloat16* __restrict__ mb,
    const float* __restrict__ m2, const float* __restrict__ q2,
    unsigned* __restrict__ candK) {
    __shared__ __align__(16) unsigned char smem[33280];  // 32KB tile + 512B m2s
    const int tid = threadIdx.x;
    const int w = tid >> 6;
    const int lane = tid & 63;
    const int i16 = lane & 15;
    const int g = lane >> 4;
    const int row0 = blockIdx.x * BROWS;
    const int col0 = blockIdx.y * COLS_PER_SPLIT;

    // ---- A fragments: 2 row-tiles x 4 k-steps ----
    bf16x8 afrag[2][4];
#pragma unroll
    for (int ti = 0; ti < 2; ++ti) {
        const __hip_bfloat16* qrow =
            qb + (size_t)(row0 + w * 32 + ti * 16 + i16) * DIM;
#pragma unroll
        for (int ks = 0; ks < 4; ++ks)
            afrag[ti][ks] = *reinterpret_cast<const bf16x8*>(qrow + ks * 32 + g * 8);
    }
    // ---- q2 for this lane's 8 C-rows (D-layout row = g*4 + reg) ----
    float q2v[8];
#pragma unroll
    for (int rr = 0; rr < 8; ++rr)
        q2v[rr] = q2[row0 + w * 32 + (rr >> 2) * 16 + g * 4 + (rr & 3)];

    // ---- sorted lists (packed keys), 8 rows x 4, ascending ----
    unsigned lst[8][LLIST];
#pragma unroll
    for (int rr = 0; rr < 8; ++rr)
#pragma unroll
        for (int j = 0; j < LLIST; ++j) lst[rr][j] = 0xFFFFFFFFu;

    // ---- loop-invariant addressing ----
    const int lds_base = i16 * 256 + ((g ^ (i16 & 7)) << 4);
    int soff[8];
#pragma unroll
    for (int it = 0; it < 8; ++it) {
        int fg = w * 512 + it * 64 + lane;
        int c = fg >> 4, sg = fg & 15;
        int gk = (sg & 8) | ((sg ^ c) & 7);
        soff[it] = c * DIM + gk * 8;
    }
    const __hip_bfloat16* mbt = mb + (size_t)col0 * DIM;

    for (int t = 0; t < ITERS; ++t) {
        __syncthreads();  // all waves done reading previous tile
#pragma unroll
        for (int it = 0; it < 8; ++it)
            gl2lds16(mbt + soff[it], smem + w * 8192 + it * 1024);
        if (tid < 32) {
            float4 v = *reinterpret_cast<const float4*>(m2 + col0 + t * 128 + tid * 4);
            *reinterpret_cast<float4*>(smem + 32768 + tid * 16) = v;
        }
        mbt += 128 * DIM;
        __syncthreads();

        const float* m2f = (const float*)(smem + 32768);
#pragma unroll
        for (int half = 0; half < 2; ++half) {
            f32x4 acc[2][4];
#pragma unroll
            for (int ti = 0; ti < 2; ++ti)
#pragma unroll
                for (int ct = 0; ct < 4; ++ct) acc[ti][ct] = (f32x4){0.f, 0.f, 0.f, 0.f};
#pragma unroll
            for (int ks = 0; ks < 4; ++ks) {
                const unsigned char* bp = smem + (lds_base ^ (ks << 6)) + half * 16384;
#pragma unroll
                for (int ct = 0; ct < 4; ++ct) {
                    bf16x8 bfr = *reinterpret_cast<const bf16x8*>(bp + ct * 4096);
                    acc[0][ct] = __builtin_amdgcn_mfma_f32_16x16x32_bf16(
                        afrag[0][ks], bfr, acc[0][ct], 0, 0, 0);
                    acc[1][ct] = __builtin_amdgcn_mfma_f32_16x16x32_bf16(
                        afrag[1][ks], bfr, acc[1][ct], 0, 0, 0);
                }
            }
            float m2v[4];
            unsigned colv[4];
#pragma unroll
            for (int ct = 0; ct < 4; ++ct) {
                m2v[ct] = m2f[half * 64 + ct * 16 + i16];
                colv[ct] = (unsigned)(col0 + t * 128 + half * 64 + ct * 16 + i16);
            }
#pragma unroll
            for (int ti = 0; ti < 2; ++ti) {
#pragma unroll
                for (int r = 0; r < 4; ++r) {
                    const int rr = ti * 4 + r;
#pragma unroll
                    for (int ct = 0; ct < 4; ++ct) {
                        float d2 = fmaf(-2.f, acc[ti][ct][r], m2v[ct]) + q2v[rr];
                        unsigned k = (__float_as_uint(d2) & 0xFFFFC000u) | colv[ct];
                        INS4(lst[rr], k);
                    }
                }
            }
        }
    }

    __syncthreads();  // tile LDS dead; overlay merge buffer

    // ---- phase 1: SNAPSHOT partner's 4 keys, then insert (r4 bugfix) ----
#pragma unroll
    for (int rr = 0; rr < 8; ++rr) {
        unsigned pv[LLIST];
#pragma unroll
        for (int j = 0; j < LLIST; ++j)
            pv[j] = (unsigned)__shfl_xor((int)lst[rr][j], 8, 64);
#pragma unroll
        for (int j = 0; j < LLIST; ++j) INS4(lst[rr], pv[j]);
    }
    // ---- dump: 8 lanes x 4 keys per row, stride 33 ----
    unsigned* MG = (unsigned*)smem;  // [128][33]
    if (i16 < 8) {
#pragma unroll
        for (int rr = 0; rr < 8; ++rr) {
            int row = w * 32 + (rr >> 2) * 16 + g * 4 + (rr & 3);
#pragma unroll
            for (int j = 0; j < LLIST; ++j)
                MG[row * 33 + i16 * LLIST + j] = lst[rr][j];
        }
    }
    __syncthreads();
    // ---- phase 2: thread per row, branchless depth-8 over 32 keys ----
    if (tid < BROWS) {
        unsigned bk[TSEL];
#pragma unroll
        for (int j = 0; j < TSEL; ++j) bk[j] = 0xFFFFFFFFu;
        for (int c = 0; c < 32; ++c) {
            unsigned k = MG[tid * 33 + c];
#pragma unroll
            for (int i = TSEL - 1; i >= 1; --i)
                bk[i] = max(bk[i - 1], min(bk[i], k));
            bk[0] = min(bk[0], k);
        }
        size_t base = (size_t)(row0 + tid) * (SPLITS * TSEL) + blockIdx.y * TSEL;
        *reinterpret_cast<uint4*>(candK + base) =
            make_uint4(bk[0], bk[1], bk[2], bk[3]);
        *reinterpret_cast<uint4*>(candK + base + 4) =
            make_uint4(bk[4], bk[5], bk[6], bk[7]);
    }
}

// ---------------------------------------------------------------------------
// Kernel C: global merge. Thread per row: 64 packed keys (already global-col,
// directly comparable) -> top-16 -> candidate indices.
// ---------------------------------------------------------------------------
__global__ void merge_kernel(const unsigned* __restrict__ candK,
                             int* __restrict__ candI2) {
    int row = blockIdx.x * blockDim.x + threadIdx.x;
    const unsigned* ck = candK + (size_t)row * (SPLITS * TSEL);
    unsigned v[TSEL2];
#pragma unroll
    for (int j = 0; j < TSEL2; ++j) v[j] = 0xFFFFFFFFu;
    for (int s4 = 0; s4 < 16; ++s4) {
        uint4 kk = reinterpret_cast<const uint4*>(ck)[s4];
        unsigned ks[4] = {kk.x, kk.y, kk.z, kk.w};
#pragma unroll
        for (int e = 0; e < 4; ++e) {
            unsigned k = ks[e];
#pragma unroll
            for (int i = TSEL2 - 1; i >= 1; --i)
                v[i] = max(v[i - 1], min(v[i], k));
            v[0] = min(v[0], k);
        }
    }
#pragma unroll
    for (int j = 0; j < TSEL2; ++j)
        candI2[(size_t)row * TSEL2 + j] = (int)(v[j] & 0x3FFFu);
}

// ---------------------------------------------------------------------------
// Kernel D: exact fp32 re-rank of 16 candidates/query + adaptive-KNN output.
// Wave per query: lane = (cand = lane>>2, quarter qd = lane&3); each quad
// reads one mem row cooperatively, quad-reduces the dot, then 5 shuffle-
// argmin extractions -> exact top-5.
// ---------------------------------------------------------------------------
__global__ __launch_bounds__(256) void finalize_kernel(
    const float* __restrict__ q, const float* __restrict__ mem,
    const float* __restrict__ q2, const float* __restrict__ m2,
    const int* __restrict__ candI2, const float* __restrict__ scaleb,
    float* __restrict__ out) {
    int wv = threadIdx.x >> 6, lane = threadIdx.x & 63;
    int n = blockIdx.x * 4 + wv;
    int cand = lane >> 2, qd = lane & 3;
    int ci = candI2[(size_t)n * TSEL2 + cand];
    const float4* qr = reinterpret_cast<const float4*>(q + (size_t)n * DIM) + qd * 8;
    const float4* mr = reinterpret_cast<const float4*>(mem + (size_t)ci * DIM) + qd * 8;
    float dot = 0.f;
#pragma unroll
    for (int k = 0; k < 8; ++k) {
        float4 a = qr[k], b = mr[k];
        dot = fmaf(a.x, b.x, fmaf(a.y, b.y, fmaf(a.z, b.z, fmaf(a.w, b.w, dot))));
    }
    dot += __shfl_xor(dot, 1, 64);
    dot += __shfl_xor(dot, 2, 64);
    float v = (qd == 0) ? (q2[n] + m2[ci] - 2.f * dot) : BIGF;

    float dk[KNN]; int ik[KNN];
#pragma unroll
    for (int r = 0; r < KNN; ++r) {
        float mv = v; int ml = lane;
#pragma unroll
        for (int off = 32; off > 0; off >>= 1) {
            float ov = __shfl_xor(mv, off, 64);
            int   ol = __shfl_xor(ml, off, 64);
            if (ov < mv || (ov == mv && ol < ml)) { mv = ov; ml = ol; }
        }
        dk[r] = sqrtf(fmaxf(mv, 1e-12f));
        ik[r] = __shfl(ci, ml, 64);
        if (lane == ml) v = BIGF;
    }
    if (lane == 0) {
        float dmin = dk[0];
        float se = 0.f, wd = 0.f, sm = 0.f, ssc = 0.f;
#pragma unroll
        for (int j = 0; j < KNN; ++j) {
            float e = expf(-(dk[j] - dmin));
            se += e;
            wd = fmaf(e, dk[j], wd);
            sm += dk[j];
            ssc += scaleb[ik[j]];
        }
        wd /= se;
        float scale = ssc * 0.2f;
        float nd = wd / fmaxf(scale, 1e-6f);
        float mean = sm * 0.2f;
        float var = 0.f;
#pragma unroll
        for (int j = 0; j < KNN; ++j) {
            float dd = dk[j] - mean;
            var = fmaf(dd, dd, var);
        }
        var *= 0.2f;
        float cons = sqrtf(var) / fmaxf(mean, 1e-6f);
        out[n] = nd * (1.f + 0.5f * cons);
    }
}

// ---------------------------------------------------------------------------
// ws: q2[N] | m2[M] | qb bf16 | mb bf16 | candK[N*64] u32 | candI2[N*16] i32
// (~13.2 MB)
// ---------------------------------------------------------------------------
extern "C" void kernel_launch(void* const* d_in, const int* in_sizes, int n_in,
                              void* d_out, int out_size, void* d_ws,
                              size_t ws_size, hipStream_t stream) {
    const float* query  = (const float*)d_in[0];
    const float* mem    = (const float*)d_in[1];
    const float* scaleb = (const float*)d_in[2];
    float* out = (float*)d_out;

    float* q2 = (float*)d_ws;
    float* m2 = q2 + N_Q;
    __hip_bfloat16* qb = (__hip_bfloat16*)(m2 + N_M);
    __hip_bfloat16* mb = qb + (size_t)N_Q * DIM;
    unsigned* candK = (unsigned*)(mb + (size_t)N_M * DIM);
    int* candI2 = (int*)(candK + (size_t)N_Q * SPLITS * TSEL);

    prep_kernel<<<(N_Q + N_M) / 4, 256, 0, stream>>>(query, mem, q2, m2, qb, mb);
    dim3 gridB(N_Q / BROWS, SPLITS);
    knn_tops_kernel<<<gridB, 256, 0, stream>>>(qb, mb, m2, q2, candK);
    merge_kernel<<<N_Q / 256, 256, 0, stream>>>(candK, candI2);
    finalize_kernel<<<N_Q / 4, 256, 0, stream>>>(query, mem, q2, m2, candI2,
                                                 scaleb, out);
}